// Round 13
// baseline (152.186 us; speedup 1.0000x reference)
//
#include <hip/hip_runtime.h>
#include <hip/hip_bf16.h>

typedef __attribute__((ext_vector_type(8))) short bf16x8;
typedef __attribute__((ext_vector_type(4))) float f32x4;

#define FSW(c) (((c) >> 1) & 3)

static __device__ __forceinline__ uint bf16rne(float f) {
    uint u = __float_as_uint(f);
    return (u + 0x7fffu + ((u >> 16) & 1u)) >> 16;
}

// K_prep1: blocks [0,1024): Wf/wsq prep; blocks [1024,2048): style.
__global__ void k_prep1(const float* __restrict__ weight, ushort* __restrict__ Wf,
                        float* __restrict__ wsq, const float* __restrict__ w,
                        const float* __restrict__ aw, const float* __restrict__ ab,
                        float* __restrict__ style) {
    if (blockIdx.x < 1024) {
        int t = blockIdx.x * 256 + threadIdx.x;          // (o,c)
        int o = t >> 9, c = t & 511;
        int grp = o >> 5, rr = o & 31, fm = rr >> 4, l15r = rr & 15;
        int chunkid = c >> 5, kgw = (c >> 3) & 3, kk = c & 7;
        int lanew = kgw * 16 + l15r;
        const float* wp = weight + (size_t)t * 9;
        size_t G = (size_t)(grp * 16 + chunkid);
        size_t base = G * 9216 + (size_t)fm * 512 + (size_t)lanew * 8 + kk;
        float sq = 0.f;
        #pragma unroll
        for (int j = 0; j < 9; ++j) {
            float v = wp[j];
            sq += v * v;
            Wf[base + (size_t)j * 1024] = (ushort)bf16rne(v);
        }
        wsq[t] = sq;
    } else {
        int idx = (blockIdx.x - 1024) * 4 + (threadIdx.x >> 6);
        int lane = threadIdx.x & 63;
        int b = idx >> 9, c = idx & 511;
        const float* wp = w + b * 512;
        const float* ap = aw + (size_t)c * 512;
        float s = 0.f;
        #pragma unroll
        for (int i = 0; i < 8; ++i) s += wp[lane + i * 64] * ap[lane + i * 64];
        #pragma unroll
        for (int m = 32; m; m >>= 1) s += __shfl_xor(s, m, 64);
        if (lane == 0) style[idx] = s + ab[c] + 1.0f;
    }
}

// K_prep2: blocks [0,1024): sigma; blocks [1024,1536): premod xb (NHWC bf16).
__global__ void k_prep2(const float* __restrict__ style, const float* __restrict__ wsq,
                        float* __restrict__ sigma, const float* __restrict__ x,
                        ushort* __restrict__ xb) {
    if (blockIdx.x < 1024) {
        int idx = blockIdx.x * 4 + (threadIdx.x >> 6);
        int lane = threadIdx.x & 63;
        int b = idx >> 9, o = idx & 511;
        const float* sp = style + b * 512;
        const float* qp = wsq + (size_t)o * 512;
        float s = 0.f;
        #pragma unroll
        for (int i = 0; i < 8; ++i) {
            float st = sp[lane + i * 64];
            s += st * st * qp[lane + i * 64];
        }
        #pragma unroll
        for (int m = 32; m; m >>= 1) s += __shfl_xor(s, m, 64);
        if (lane == 0) sigma[idx] = rsqrtf(s + 1e-8f);
    } else {
        int bid = blockIdx.x - 1024;     // b*64 + y
        int b = bid >> 6, y = bid & 63;
        int xcol = threadIdx.x >> 2, cg = threadIdx.x & 3;
        const float* sp = style + b * 512;
        #pragma unroll 1
        for (int cb = 0; cb < 16; ++cb) {
            int c0 = cb * 32 + cg * 8;
            float v[8];
            #pragma unroll
            for (int j = 0; j < 8; ++j)
                v[j] = x[((size_t)(b * 512 + c0 + j) * 64 + y) * 64 + xcol] * sp[c0 + j];
            uint4 pk;
            pk.x = bf16rne(v[0]) | (bf16rne(v[1]) << 16);
            pk.y = bf16rne(v[2]) | (bf16rne(v[3]) << 16);
            pk.z = bf16rne(v[4]) | (bf16rne(v[5]) << 16);
            pk.w = bf16rne(v[6]) | (bf16rne(v[7]) << 16);
            *(uint4*)&xb[((size_t)(b * 64 + y) * 64 + xcol) * 512 + c0] = pk;
        }
    }
}

// A-frag load: tap-row DY of chunk CC into SL (12 uint4: dx*4+fm, fm over 64 o)
#define ALOAD(SL, DY, CC) { \
    _Pragma("unroll") for (int dx_ = 0; dx_ < 3; ++dx_) \
    _Pragma("unroll") for (int fm_ = 0; fm_ < 4; ++fm_) \
        SL[dx_ * 4 + fm_] = *(const uint4*)((fm_ < 2 ? Wbase0 : Wbase1) \
            + (size_t)(CC) * 9216 + ((DY) * 3 + dx_) * 1024 + (fm_ & 1) * 512); }

// 24 MFMAs: A tap-row AARR (4 fm) vs bv[6], output row H
#define HGROUP(AARR, H) \
    _Pragma("unroll") for (int dx_ = 0; dx_ < 3; ++dx_) \
    _Pragma("unroll") for (int q_ = 0; q_ < 2; ++q_) \
    _Pragma("unroll") for (int fm_ = 0; fm_ < 4; ++fm_) \
        acc[fm_][(H) * 2 + q_] = __builtin_amdgcn_mfma_f32_16x16x32_bf16( \
            *(const bf16x8*)&AARR[dx_ * 4 + fm_], bv[dx_ * 2 + q_], \
            acc[fm_][(H) * 2 + q_], 0, 0, 0);

// one input-row phase: 6 ds_reads then MFMA cluster(s)
#define ROW(R, MFMAS) { \
    bf16x8 bv[6]; \
    _Pragma("unroll") for (int dx_ = 0; dx_ < 3; ++dx_) \
    _Pragma("unroll") for (int q_ = 0; q_ < 2; ++q_) { \
        int ci_ = dx_ + cb32 + q_ * 16 + l15; \
        bv[dx_ * 2 + q_] = *(const bf16x8*)&sX[cur][((R) * 66 + ci_) * 32 + ((kg ^ FSW(ci_)) * 8)]; \
    } \
    __builtin_amdgcn_s_setprio(1); \
    MFMAS \
    __builtin_amdgcn_s_setprio(0); }

// xs <- xb chunk CC (4 input rows)
#define XLOAD(CC) { \
    _Pragma("unroll") for (int p_ = 0; p_ < 4; ++p_) { \
        int yy_ = y0 - 1 + p_; \
        xs[p_] = ((unsigned)yy_ < 64u) \
               ? *(const uint4*)(xrow_base + (size_t)yy_ * 32768 + (CC) * 32) \
               : make_uint4(0u, 0u, 0u, 0u); \
    } }

// commit xs -> buffer BUF
#define XWRITE(BUF) { \
    _Pragma("unroll") for (int p_ = 0; p_ < 4; ++p_) \
        *(uint4*)&sX[BUF][(p_ * 66 + colpos) * 32 + sslot] = xs[p_]; }

// one chunk. Entry: A0_=dy0(CCI), A1_=dy1(CCI). Exit: A1_=dy0(NCC), A0_=dy1(NCC).
#define CHUNK(CCI, NCC, A0_, A1_) { \
    XLOAD(NCC) \
    ROW(0, HGROUP(A0_, 0)) \
    ROW(1, HGROUP(A0_, 1) HGROUP(A1_, 0)) \
    ALOAD(A0_, 2, CCI)            /* dy0 dead -> dy2 this chunk (JIT) */ \
    ROW(2, HGROUP(A1_, 1) HGROUP(A0_, 0)) \
    ALOAD(A1_, 0, NCC)            /* dy1 dead -> dy0 next chunk */ \
    ROW(3, HGROUP(A0_, 1)) \
    XWRITE(cur ^ 1) \
    __syncthreads(); \
    cur ^= 1; \
    ALOAD(A0_, 1, NCC)            /* dy2 dead -> dy1 next chunk */ \
}

// K4: implicit-GEMM conv, 16x16x32 MFMA. Block: 128 o x 128 px (2 rows),
// wave grid 2(o) x 2(cols): wave = 64o x (2 rows x 32 cols). Per chunk/wave:
// 24 ds_read_b128 feed 144 MFMA (6 MFMA/read, 2x R10's ratio). 2-array A
// ping-pong (R8-verified cadence), XCD-aware bid remap, 2 waves/SIMD.
__global__ __launch_bounds__(256, 2) void k_conv(
    const ushort* __restrict__ xb, const ushort* __restrict__ Wf,
    const float* __restrict__ sigma, const float* __restrict__ bias,
    float* __restrict__ out) {

    __shared__ ushort sX[2][4 * 66 * 32];   // [buf][row][col][32ch], swizzled 16B slots

    const int tid = threadIdx.x, bid = blockIdx.x;
    const int ob = bid >> 8;                               // 0..3
    const int pb = ((bid & 7) << 5) | ((bid >> 3) & 31);   // b = bid&7, y-tile
    const int b = pb >> 5, y0 = (pb & 31) * 2;
    const int o0 = ob * 128;
    const int wv = tid >> 6, lane = tid & 63;
    const int l15 = lane & 15, kg = lane >> 4;
    const int wr = wv >> 1;              // o 64-half
    const int cb32 = (wv & 1) * 32;      // col 32-half

    // x staging role: thread owns (scol, skg); stages all 4 input rows
    const int scol = (tid >> 2) & 63;
    const int skg = tid & 3;
    const int colpos = scol + 1;
    const int sslot = (skg ^ FSW(colpos)) * 8;
    const ushort* xrow_base = xb + ((size_t)(b * 64) * 64 + scol) * 512 + skg * 8;

    // A bases: two 32-o groups make this wave's 64 o rows
    const ushort* Wbase0 = Wf + (size_t)(ob * 4 + wr * 2) * 147456 + lane * 8;
    const ushort* Wbase1 = Wbase0 + 147456;

    f32x4 acc[4][4];                     // [fm][h*2+q]
    #pragma unroll
    for (int i = 0; i < 4; ++i)
        #pragma unroll
        for (int j = 0; j < 4; ++j) acc[i][j] = (f32x4){0.f, 0.f, 0.f, 0.f};

    // zero halo pads (colpos 0 and 65, both buffers) once
    if (tid < 64) {
        int buf = tid >> 5, rem = tid & 31;
        int r = rem >> 3, side = (rem >> 2) & 1, sl = rem & 3;
        int cp = side * 65;
        *(uint4*)&sX[buf][(r * 66 + cp) * 32 + sl * 8] = make_uint4(0u, 0u, 0u, 0u);
    }

    uint4 xs[4];
    // prologue: stage chunk 0 into buf 0
    XLOAD(0)
    XWRITE(0)

    uint4 aX[12], aY[12];
    ALOAD(aX, 0, 0) ALOAD(aY, 1, 0)
    __syncthreads();

    int cur = 0;
    #pragma unroll 1
    for (int it = 0; it < 8; ++it) {
        const int c0 = it * 2, c1 = it * 2 + 1, c2 = (it * 2 + 2) & 15; // wrap: harmless
        CHUNK(c0, c1, aX, aY)
        CHUNK(c1, c2, aY, aX)
    }

    // epilogue: out = acc * sigma + bias
    const float* sigb = sigma + b * 512;
    #pragma unroll
    for (int fm = 0; fm < 4; ++fm) {
        #pragma unroll
        for (int j = 0; j < 4; ++j) {
            int o = o0 + wr * 64 + fm * 16 + kg * 4 + j;
            float sg = sigb[o];
            float bs = bias[o];
            float* op = out + ((size_t)(b * 512 + o) * 64 + y0) * 64;
            #pragma unroll
            for (int h = 0; h < 2; ++h)
                #pragma unroll
                for (int q = 0; q < 2; ++q)
                    op[h * 64 + cb32 + q * 16 + l15] = acc[fm][h * 2 + q][j] * sg + bs;
        }
    }
}

extern "C" void kernel_launch(void* const* d_in, const int* in_sizes, int n_in,
                              void* d_out, int out_size, void* d_ws, size_t ws_size,
                              hipStream_t stream) {
    const float* x    = (const float*)d_in[0];
    const float* w    = (const float*)d_in[1];
    const float* wt   = (const float*)d_in[2];
    const float* bias = (const float*)d_in[3];
    const float* aw   = (const float*)d_in[4];
    const float* ab   = (const float*)d_in[5];
    float* out = (float*)d_out;

    // ws layout: style(16KB) | sigma(16KB) | wsq(1MB) | Wf(4.5MB) | xb(32MB)
    float* style  = (float*)d_ws;
    float* sigmap = style + 4096;
    float* wsq    = sigmap + 4096;
    ushort* Wf    = (ushort*)(wsq + 512 * 512);
    ushort* xbm   = Wf + 2359296;

    k_prep1<<<2048, 256, 0, stream>>>(wt, Wf, wsq, w, aw, ab, style);
    k_prep2<<<1536, 256, 0, stream>>>(style, wsq, sigmap, x, xbm);
    k_conv <<<1024, 256, 0, stream>>>(xbm, Wf, sigmap, bias, out);
}

// Round 14
// 142.123 us; speedup vs baseline: 1.0708x; 1.0708x over previous
//
#include <hip/hip_runtime.h>
#include <hip/hip_bf16.h>

typedef __attribute__((ext_vector_type(8))) short bf16x8;
typedef __attribute__((ext_vector_type(4))) float f32x4;

#define FSW(c) (((c) >> 1) & 3)

typedef __attribute__((address_space(3))) unsigned int lds_uint;
typedef const __attribute__((address_space(1))) unsigned int gl_uint;

static __device__ __forceinline__ void gll16(const ushort* g, ushort* l) {
    __builtin_amdgcn_global_load_lds((gl_uint*)g, (lds_uint*)l, 16, 0, 0);
}

static __device__ __forceinline__ uint bf16rne(float f) {
    uint u = __float_as_uint(f);
    return (u + 0x7fffu + ((u >> 16) & 1u)) >> 16;
}

// K_prep1: blocks [0,1024): Wf/wsq prep; blocks [1024,2048): style.
__global__ void k_prep1(const float* __restrict__ weight, ushort* __restrict__ Wf,
                        float* __restrict__ wsq, const float* __restrict__ w,
                        const float* __restrict__ aw, const float* __restrict__ ab,
                        float* __restrict__ style) {
    if (blockIdx.x < 1024) {
        int t = blockIdx.x * 256 + threadIdx.x;          // (o,c)
        int o = t >> 9, c = t & 511;
        int grp = o >> 5, rr = o & 31, fm = rr >> 4, l15r = rr & 15;
        int chunkid = c >> 5, kgw = (c >> 3) & 3, kk = c & 7;
        int lanew = kgw * 16 + l15r;
        const float* wp = weight + (size_t)t * 9;
        size_t G = (size_t)(grp * 16 + chunkid);
        size_t base = G * 9216 + (size_t)fm * 512 + (size_t)lanew * 8 + kk;
        float sq = 0.f;
        #pragma unroll
        for (int j = 0; j < 9; ++j) {
            float v = wp[j];
            sq += v * v;
            Wf[base + (size_t)j * 1024] = (ushort)bf16rne(v);
        }
        wsq[t] = sq;
    } else {
        int idx = (blockIdx.x - 1024) * 4 + (threadIdx.x >> 6);
        int lane = threadIdx.x & 63;
        int b = idx >> 9, c = idx & 511;
        const float* wp = w + b * 512;
        const float* ap = aw + (size_t)c * 512;
        float s = 0.f;
        #pragma unroll
        for (int i = 0; i < 8; ++i) s += wp[lane + i * 64] * ap[lane + i * 64];
        #pragma unroll
        for (int m = 32; m; m >>= 1) s += __shfl_xor(s, m, 64);
        if (lane == 0) style[idx] = s + ab[c] + 1.0f;
    }
}

// K_prep2: blocks [0,1024): sigma; blocks [1024,1536): premod xb (NHWC bf16).
__global__ void k_prep2(const float* __restrict__ style, const float* __restrict__ wsq,
                        float* __restrict__ sigma, const float* __restrict__ x,
                        ushort* __restrict__ xb) {
    if (blockIdx.x < 1024) {
        int idx = blockIdx.x * 4 + (threadIdx.x >> 6);
        int lane = threadIdx.x & 63;
        int b = idx >> 9, o = idx & 511;
        const float* sp = style + b * 512;
        const float* qp = wsq + (size_t)o * 512;
        float s = 0.f;
        #pragma unroll
        for (int i = 0; i < 8; ++i) {
            float st = sp[lane + i * 64];
            s += st * st * qp[lane + i * 64];
        }
        #pragma unroll
        for (int m = 32; m; m >>= 1) s += __shfl_xor(s, m, 64);
        if (lane == 0) sigma[idx] = rsqrtf(s + 1e-8f);
    } else {
        int bid = blockIdx.x - 1024;     // b*64 + y
        int b = bid >> 6, y = bid & 63;
        int xcol = threadIdx.x >> 2, cg = threadIdx.x & 3;
        const float* sp = style + b * 512;
        #pragma unroll 1
        for (int cb = 0; cb < 16; ++cb) {
            int c0 = cb * 32 + cg * 8;
            float v[8];
            #pragma unroll
            for (int j = 0; j < 8; ++j)
                v[j] = x[((size_t)(b * 512 + c0 + j) * 64 + y) * 64 + xcol] * sp[c0 + j];
            uint4 pk;
            pk.x = bf16rne(v[0]) | (bf16rne(v[1]) << 16);
            pk.y = bf16rne(v[2]) | (bf16rne(v[3]) << 16);
            pk.z = bf16rne(v[4]) | (bf16rne(v[5]) << 16);
            pk.w = bf16rne(v[6]) | (bf16rne(v[7]) << 16);
            *(uint4*)&xb[((size_t)(b * 64 + y) * 64 + xcol) * 512 + c0] = pk;
        }
    }
}

// A-frag load: tap-row DY of chunk CC into SL (6 uint4: dx*2+fm)
#define ALOAD(SL, DY, CC) { \
    const ushort* p_ = Wbase + (size_t)(CC) * 9216 + (DY) * 3072; \
    _Pragma("unroll") for (int q_ = 0; q_ < 6; ++q_) \
        SL[q_] = *(const uint4*)(p_ + q_ * 512); }

#define MM(AV, BV, FM, FN) \
    acc[FM][FN] = __builtin_amdgcn_mfma_f32_16x16x32_bf16( \
        *(const bf16x8*)&(AV), (BV), acc[FM][FN], 0, 0, 0)

// 24 MFMAs: A tap-row AARR vs bv[], output row H
#define HGROUP(AARR, H) \
    _Pragma("unroll") for (int dx_ = 0; dx_ < 3; ++dx_) { \
      _Pragma("unroll") for (int q_ = 0; q_ < 4; ++q_) { \
        MM(AARR[dx_ * 2 + 0], bv[dx_ * 4 + q_], 0, (H) * 4 + q_); \
        MM(AARR[dx_ * 2 + 1], bv[dx_ * 4 + q_], 1, (H) * 4 + q_); \
      } }

// one input-row phase: 12 ds_reads then MFMA cluster(s)
#define ROW(R, MFMAS) { \
    bf16x8 bv[12]; \
    _Pragma("unroll") for (int dx_ = 0; dx_ < 3; ++dx_) \
    _Pragma("unroll") for (int q_ = 0; q_ < 4; ++q_) { \
        int ci_ = dx_ + q_ * 16 + l15; \
        bv[dx_ * 4 + q_] = *(const bf16x8*)&sX[cur][((R) * 66 + ci_) * 32 + ((kg ^ FSW(ci_)) * 8)]; \
    } \
    __builtin_amdgcn_s_setprio(1); \
    MFMAS \
    __builtin_amdgcn_s_setprio(0); }

// stage chunk CC into buffer BUF via global_load_lds DMA (fire-and-forget).
// Per-lane pre-swizzled global source + linear LDS dest (m173 pattern).
// Halo rows (block-uniform invalid yy) are pre-zeroed once and skipped here.
#define XSTAGE(BUF, CC) { \
    _Pragma("unroll") for (int p_ = 0; p_ < 4; ++p_) { \
        int yy_ = y0 - 1 + p_; \
        if ((unsigned)yy_ < 64u) \
            gll16(srcb + (size_t)yy_ * 32768 + (CC) * 32, \
                  &sX[BUF][(p_ * 66 + wv * 16 + 1) * 32]); \
    } }

// K4: implicit-GEMM conv, 16x16x32 MFMA. Block: 128 o x 128 px (2 rows),
// 4 waves of 32o x 128px. R10 cadence exactly; staging via global_load_lds
// (no VGPR round-trip, no ds_writes). XCD-aware bid remap (T1).
__global__ __launch_bounds__(256, 2) void k_conv(
    const ushort* __restrict__ xb, const ushort* __restrict__ Wf,
    const float* __restrict__ sigma, const float* __restrict__ bias,
    float* __restrict__ out) {

    __shared__ ushort sX[2][4 * 66 * 32];   // [buf][row][col][32ch], swizzled 16B slots

    const int tid = threadIdx.x, bid = blockIdx.x;
    const int ob = bid >> 8;                               // 0..3
    const int pb = ((bid & 7) << 5) | ((bid >> 3) & 31);   // b = bid&7, y-tile
    const int b = pb >> 5, y0 = (pb & 31) * 2;
    const int o0 = ob * 128;
    const int wv = tid >> 6, lane = tid & 63;
    const int l15 = lane & 15, kg = lane >> 4;

    // gll staging role: wave wv owns cols [16wv,16wv+16); lane = (scol_local, skg)
    const int scol = wv * 16 + (lane >> 2);
    const int skg = lane & 3;
    // pre-swizzled per-lane source: element (scol, skg^FSW(scol+1))
    const ushort* srcb = xb + ((size_t)(b * 64) * 64 + scol) * 512
                       + (size_t)((skg ^ FSW(scol + 1)) * 8);

    const int grp = ob * 4 + wv;
    const ushort* Wbase = Wf + (size_t)grp * 147456 + lane * 8;

    f32x4 acc[2][8];
    #pragma unroll
    for (int i = 0; i < 2; ++i)
        #pragma unroll
        for (int j = 0; j < 8; ++j) acc[i][j] = (f32x4){0.f, 0.f, 0.f, 0.f};

    // zero halo pads (colpos 0 and 65, both buffers) once
    if (tid < 64) {
        int buf = tid >> 5, rem = tid & 31;
        int r = rem >> 3, side = (rem >> 2) & 1, sl = rem & 3;
        int cp = side * 65;
        *(uint4*)&sX[buf][(r * 66 + cp) * 32 + sl * 8] = make_uint4(0u, 0u, 0u, 0u);
    }
    // zero the block-uniform halo row once (y0==0: row 0; y0==62: row 3), both buffers
    if (y0 == 0 || y0 == 62) {
        const int r = (y0 == 0) ? 0 : 3;
        #pragma unroll 1
        for (int i = tid; i < 528; i += 256) {
            int buf = i >= 264, j = (i >= 264) ? i - 264 : i;
            *(uint4*)&sX[buf][(r * 66 + (j >> 2)) * 32 + (j & 3) * 8] = make_uint4(0u, 0u, 0u, 0u);
        }
    }

    // prologue: DMA chunk 0 into buf 0; A-frags for dy0..dy2
    XSTAGE(0, 0)
    uint4 a0[6], a1[6], a2[6];
    ALOAD(a0, 0, 0) ALOAD(a1, 1, 0) ALOAD(a2, 2, 0)
    __syncthreads();

    int cur = 0;
    #pragma unroll 1
    for (int cci = 0; cci < 16; ++cci) {
        const int ncc = (cci + 1) & 15;   // wrap: harmless in-bounds reload

        // fire-and-forget DMA of next chunk into the dead buffer
        XSTAGE(cur ^ 1, ncc)

        // input-row phases; B-frag shared across both h consumers
        ROW(0, HGROUP(a0, 0))
        ROW(1, HGROUP(a0, 1) HGROUP(a1, 0))
        ALOAD(a0, 0, ncc)                 // dy0 dead after ROW1
        ROW(2, HGROUP(a1, 1) HGROUP(a2, 0))
        ALOAD(a1, 1, ncc)                 // dy1 dead after ROW2
        ROW(3, HGROUP(a2, 1))

        __syncthreads();
        cur ^= 1;
        ALOAD(a2, 2, ncc)                 // dy2 first used 2 phases into next chunk
    }

    // epilogue: out = acc * sigma + bias
    const float* sigb = sigma + b * 512;
    #pragma unroll
    for (int fm = 0; fm < 2; ++fm) {
        #pragma unroll
        for (int j = 0; j < 4; ++j) {
            int o = o0 + wv * 32 + fm * 16 + kg * 4 + j;
            float sg = sigb[o];
            float bs = bias[o];
            float* op = out + ((size_t)(b * 512 + o) * 64 + y0) * 64;
            #pragma unroll
            for (int fn = 0; fn < 8; ++fn)
                op[(fn >> 2) * 64 + (fn & 3) * 16 + l15] = acc[fm][fn][j] * sg + bs;
        }
    }
}

extern "C" void kernel_launch(void* const* d_in, const int* in_sizes, int n_in,
                              void* d_out, int out_size, void* d_ws, size_t ws_size,
                              hipStream_t stream) {
    const float* x    = (const float*)d_in[0];
    const float* w    = (const float*)d_in[1];
    const float* wt   = (const float*)d_in[2];
    const float* bias = (const float*)d_in[3];
    const float* aw   = (const float*)d_in[4];
    const float* ab   = (const float*)d_in[5];
    float* out = (float*)d_out;

    // ws layout: style(16KB) | sigma(16KB) | wsq(1MB) | Wf(4.5MB) | xb(32MB)
    float* style  = (float*)d_ws;
    float* sigmap = style + 4096;
    float* wsq    = sigmap + 4096;
    ushort* Wf    = (ushort*)(wsq + 512 * 512);
    ushort* xbm   = Wf + 2359296;

    k_prep1<<<2048, 256, 0, stream>>>(wt, Wf, wsq, w, aw, ab, style);
    k_prep2<<<1536, 256, 0, stream>>>(style, wsq, sigmap, x, xbm);
    k_conv <<<1024, 256, 0, stream>>>(xbm, Wf, sigmap, bias, out);
}